// Round 13
// baseline (610.852 us; speedup 1.0000x reference)
//
#include <hip/hip_runtime.h>
#include <stdint.h>

#define C 512
#define C2 262144  // 512*512

typedef __attribute__((ext_vector_type(8))) short bf16x8;
typedef __attribute__((ext_vector_type(4))) float f32x4;

__device__ __forceinline__ unsigned short f2bf(float f) {
    union { float f; uint32_t u; } v; v.f = f;
    uint32_t u = v.u;
    u += 0x7fffu + ((u >> 16) & 1u);   // round-to-nearest-even
    return (unsigned short)(u >> 16);
}
__device__ __forceinline__ float bf2f(unsigned short h) {
    union { uint32_t u; float f; } v; v.u = ((uint32_t)h) << 16;
    return v.f;
}

#define GL2LDS16(g, l) __builtin_amdgcn_global_load_lds( \
    (const __attribute__((address_space(1))) void*)(g),  \
    (__attribute__((address_space(3))) void*)(l), 16, 0, 0)

__device__ __forceinline__ bf16x8 ldsr16(const char* p) {
    bf16x8 r;
    asm volatile("ds_read_b128 %0, %1"
                 : "=v"(r)
                 : "v"((__attribute__((address_space(3))) const void*)p));
    return r;
}

__device__ __forceinline__ int nth_valid(int mask, int n) {
    int pq = 0;
    while (true) {
        if (mask & 1) { if (n == 0) return pq; --n; }
        mask >>= 1; ++pq;
    }
}

// K [o][i][3][3] fp32 ->
//   Kt  bf16 [j][o][c] = K[o][c][j]   (GEMM B operand)
//   KtT bf16 [j][i][c] = K[c][i][j]   (step-2 GEMM A operand = Ki1^T)
//   Ktf f32  [j][i][o] = K[o][i][j]   (assembly K-term, coalesced in o)
__global__ void k_transform(const float* __restrict__ K,
                            unsigned short* __restrict__ Kt,
                            unsigned short* __restrict__ KtT,
                            float* __restrict__ Ktf) {
    int t = blockIdx.x * 256 + threadIdx.x;  // t = a*512 + b
    int a = t >> 9, b = t & 511;
#pragma unroll
    for (int j = 0; j < 9; ++j) {
        float v = K[(size_t)t * 9 + j];
        unsigned short h = f2bf(v);
        Kt[(size_t)j * C2 + t] = h;
        KtT[(size_t)j * C2 + (size_t)b * C + a] = h;
        Ktf[(size_t)j * C2 + (size_t)b * C + a] = v;
    }
}

// Parallel heavy-first work-list build; 4 entries per yx (item = yx*4+quad).
__global__ void k_sched(int* __restrict__ sched) {
    __shared__ int hist[4][10];
    __shared__ int base[4][10];
    const int tid = threadIdx.x;
    if (tid < 40) ((int*)hist)[tid] = 0;
    if (tid < 4) sched[tid] = 0;
    __syncthreads();
    const int offs[5] = {0, 25, 74, 155, 276};
    int step = -1, yx = 0, V = 0;
    if (tid < 276) {
#pragma unroll
        for (int s = 0; s < 4; ++s)
            if (tid >= offs[s] && tid < offs[s + 1]) { step = s; yx = tid - offs[s]; }
        const int s_out = 5 + 2 * step, s_in = s_out - 2;
        const int y = yx / s_out, x = yx % s_out;
        int vy = 0, vx = 0;
#pragma unroll
        for (int p = 0; p < 3; ++p) {
            if (y - p >= 0 && y - p < s_in) ++vy;
            if (x - p >= 0 && x - p < s_in) ++vx;
        }
        V = vy * vx;
        atomicAdd(&hist[step][V], 1);
    }
    __syncthreads();
    if (tid < 4) {
        int acc = 0;
        for (int v = 9; v >= 1; --v) { base[tid][v] = acc; acc += hist[tid][v]; }
        for (int v = 1; v <= 9; ++v) hist[tid][v] = 0;   // reuse as cursor
    }
    __syncthreads();
    if (tid < 276) {
        const int idx = atomicAdd(&hist[step][V], 1);
        const int slot = base[step][V] + idx;
        int* list = sched + 4 + step * 484;
        list[slot * 4 + 0] = yx * 4 + 0;
        list[slot * 4 + 1] = yx * 4 + 1;
        list[slot * 4 + 2] = yx * 4 + 2;
        list[slot * 4 + 3] = yx * 4 + 3;
    }
}

// Persistent 256x256-tile MFMA GEMM, 512 threads = 8 waves (2M x 4N),
// wave tile 128x64, K-iter=64, LDS double-buffer 128KB, 1 block/CU.
// FULLY one-phase-ahead operand reads (A in aE/aO, B in bBa/bBb):
//   ph0: issue A(4)->aO        ; lgkm(4); MFMA(aE,bBa); stage A'
//   ph1: issue A(4)->aE B(4)->bBb; lgkm(8); MFMA(aO,bBa); stage B'
//   ph2: issue A(4)->aO        ; lgkm(4); MFMA(aE,bBb); vmcnt(0)+barrier
//   ph3: issue A(4)->aE B(4)->bBa (both from NXT buf, landed per end-ph2);
//        lgkm(8); MFMA(aO,bBb); barrier
// Each lgkm(N) = #reads issued THIS phase -> drains exactly the previous
// phase's reads; no phase waits on its own reads. 2 barriers/iter.
__global__ __launch_bounds__(512, 2) void k_gemm(
    const unsigned short* __restrict__ A,   // [s_in^2][512 i][512 c] bf16
    const unsigned short* __restrict__ Bm,  // [9][512 o][512 c] bf16
    unsigned short* __restrict__ Out,       // [s_out^2][512 i][512 o] bf16
    int s_in, int s_out, float alpha,
    int* __restrict__ ctr, const int* __restrict__ list, int n_items)
{
    __shared__ __align__(16) char lds[131072];
    __shared__ int s_item;

    const int tid = threadIdx.x;
    const int lane = tid & 63, wid = tid >> 6;
    const int wr = wid >> 2, wc = wid & 3;        // 2(M) x 4(N) waves
    const int l15 = lane & 15, lhi = lane >> 4;

    // staging: row = tid>>3 (+64k), col block pre-swizzled (involution w/ read)
    const int soff = (tid >> 3) * 1024 + ((((tid & 7) ^ ((tid >> 3) & 7))) << 4);
    const int t16 = tid * 16;

    // fragment reads ([256 rows][128B], XOR-swizzled 16B blocks)
    const int coff0 = ((lhi ^ (l15 & 7)) << 4);        // par0: c 0..31
    const int coff1 = (((4 + lhi) ^ (l15 & 7)) << 4);  // par1: c 32..63
    const int aoff = wr * 16384 + l15 * 128;           // + mh*8192 + mi*2048
    const int boff = 32768 + wc * 8192 + l15 * 128;    // + n*2048

    const char* Abase = (const char*)A;
    const char* Bbase = (const char*)Bm;

#define STAGE4(SRC, DSTOFF) { \
        const char* s_ = (SRC) + soff; \
        GL2LDS16(s_,          lds + (DSTOFF) + t16); \
        GL2LDS16(s_ + 65536,  lds + (DSTOFF) + 8192 + t16); \
        GL2LDS16(s_ + 131072, lds + (DSTOFF) + 16384 + t16); \
        GL2LDS16(s_ + 196608, lds + (DSTOFF) + 24576 + t16); \
    }

    for (;;) {
        __syncthreads();
        if (tid == 0) s_item = atomicAdd(ctr, 1);
        __syncthreads();
        const int itm = s_item;
        if (itm >= n_items) break;
        const int code = list[itm];
        const int yx = code >> 2, quad = code & 3;
        const int i0 = (quad & 1) * 256, o0 = (quad >> 1) * 256;
        const int y = yx / s_out, x = yx % s_out;

        int mask = 0, V = 0;
        for (int pq = 0; pq < 9; ++pq) {
            int u = y - pq / 3, v = x - pq % 3;
            if (u >= 0 && u < s_in && v >= 0 && v < s_in) { mask |= 1 << pq; ++V; }
        }

        auto slabA = [&](int pq) {
            int u = y - pq / 3, v = x - pq % 3;
            return Abase + ((size_t)(u * s_in + v) * C + i0) * (size_t)(C * 2);
        };
        auto slabB = [&](int pq) {
            return Bbase + ((size_t)pq * C + o0) * (size_t)(C * 2);
        };
        const int pq0 = nth_valid(mask, 0);
        const char* slA = slabA(pq0);
        const char* slB = slabB(pq0);
        const char* nsA = slA;
        const char* nsB = slB;
        if (V > 1) { int p1 = nth_valid(mask, 1); nsA = slabA(p1); nsB = slabB(p1); }

        f32x4 acc[8][4] = {};
        bf16x8 bBa[4], bBb[4];   // B frags par0 / par1 (one-phase-ahead)
        bf16x8 aE[4], aO[4];     // A frags (even/odd phase consumers)

        // ---- prologue: stage buf0; preload aE (mh0,par0) + bBa (par0) ----
        STAGE4(slA, 0)
        STAGE4(slB, 32768)
        asm volatile("s_waitcnt vmcnt(0)" ::: "memory");
        __builtin_amdgcn_s_barrier();
        __builtin_amdgcn_sched_barrier(0);
#pragma unroll
        for (int n = 0; n < 4; ++n)
            bBa[n] = ldsr16(lds + boff + n * 2048 + coff0);
#pragma unroll
        for (int mi = 0; mi < 4; ++mi)
            aE[mi] = ldsr16(lds + aoff + mi * 2048 + coff0);
        // no wait here: ph0's lgkm(4) drains these 8 (they are older).

        const int NI = 8 * V;
        for (int it = 0; it < NI; ++it) {
            const int itl = it & 7;
            const bool lastq = (itl == 7);
            const bool dummy = lastq && (((it >> 3) + 1) >= V);
            const char* sAe = lastq ? nsA : slA;
            const char* sBe = lastq ? nsB : slB;
            const int kb = lastq ? 0 : (itl + 1) * 128;   // next K-tile bytes
            const char* cur = lds + (it & 1) * 65536;
            const char* nxt = lds + ((it & 1) ^ 1) * 65536;

#define PHASE(PH) { \
        constexpr int mh_ = (PH) & 1; \
        constexpr int mhn_ = ((PH) + 1) & 1; \
        constexpr int parn_ = ((PH) == 3) ? 0 : (((PH) + 1) >> 1); \
        const int coffn_ = parn_ ? coff1 : coff0; \
        /* A prefetch for phase PH+1 (ph3 -> next iter ph0 from nxt buf) */ \
        { \
            const char* ab_ = ((PH) == 3) ? nxt : cur; \
            _Pragma("unroll") for (int mi = 0; mi < 4; ++mi) { \
                bf16x8 t0 = ldsr16(ab_ + aoff + mhn_ * 8192 + mi * 2048 + coffn_); \
                if constexpr (((PH) & 1) == 0) aO[mi] = t0; else aE[mi] = t0; \
            } \
        } \
        /* B prefetch: ph1 -> bBb (par1, cur), ph3 -> bBa (next par0, nxt) */ \
        if constexpr ((PH) == 1) { \
            _Pragma("unroll") for (int n = 0; n < 4; ++n) \
                bBb[n] = ldsr16(cur + boff + n * 2048 + coff1); \
        } \
        if constexpr ((PH) == 3) { \
            _Pragma("unroll") for (int n = 0; n < 4; ++n) \
                bBa[n] = ldsr16(nxt + boff + n * 2048 + coff0); \
        } \
        /* stages into nxt buf */ \
        if constexpr ((PH) == 0) { if (!dummy) STAGE4(sAe + kb, ((it & 1) ^ 1) * 65536) } \
        if constexpr ((PH) == 1) { if (!dummy) STAGE4(sBe + kb, ((it & 1) ^ 1) * 65536 + 32768) } \
        if constexpr ((PH) == 1 || (PH) == 3) { \
            asm volatile("s_waitcnt lgkmcnt(8)" ::: "memory"); \
        } else { \
            asm volatile("s_waitcnt lgkmcnt(4)" ::: "memory"); \
        } \
        __builtin_amdgcn_sched_barrier(0); \
        __builtin_amdgcn_s_setprio(1); \
        _Pragma("unroll") for (int mi = 0; mi < 4; ++mi) \
        _Pragma("unroll") for (int n = 0; n < 4; ++n) { \
            if constexpr ((PH) == 0) \
                acc[mi][n] = __builtin_amdgcn_mfma_f32_16x16x32_bf16(aE[mi], bBa[n], acc[mi][n], 0, 0, 0); \
            else if constexpr ((PH) == 1) \
                acc[4 + mi][n] = __builtin_amdgcn_mfma_f32_16x16x32_bf16(aO[mi], bBa[n], acc[4 + mi][n], 0, 0, 0); \
            else if constexpr ((PH) == 2) \
                acc[mi][n] = __builtin_amdgcn_mfma_f32_16x16x32_bf16(aE[mi], bBb[n], acc[mi][n], 0, 0, 0); \
            else \
                acc[4 + mi][n] = __builtin_amdgcn_mfma_f32_16x16x32_bf16(aO[mi], bBb[n], acc[4 + mi][n], 0, 0, 0); \
        } \
        __builtin_amdgcn_s_setprio(0); \
        if constexpr ((PH) == 2) { \
            asm volatile("s_waitcnt vmcnt(0)" ::: "memory"); \
            __builtin_amdgcn_s_barrier(); \
            __builtin_amdgcn_sched_barrier(0); \
        } \
        if constexpr ((PH) == 3) { \
            __builtin_amdgcn_s_barrier(); \
            __builtin_amdgcn_sched_barrier(0); \
        } \
    }

            PHASE(0) PHASE(1) PHASE(2) PHASE(3)
#undef PHASE

            if (lastq) {
                slA = nsA; slB = nsB;
                int vn = (it >> 3) + 2;
                if (vn < V) {
                    int pqn = nth_valid(mask, vn);
                    nsA = slabA(pqn); nsB = slabB(pqn);
                }
            }
        }
        // final ph3 left 8 ds_reads in flight targeting aE/bBa: drain before
        // the epilogue can reuse those registers.
        asm volatile("s_waitcnt lgkmcnt(0)" ::: "memory");
        __builtin_amdgcn_sched_barrier(0);

        // D layout per 16x16 frag: col(o)=lane&15, row(i)=(lane>>4)*4+reg
#pragma unroll
        for (int M = 0; M < 8; ++M) {
#pragma unroll
            for (int r = 0; r < 4; ++r) {
                const int irow = i0 + wr * 128 + M * 16 + lhi * 4 + r;
                unsigned short* op = Out + ((size_t)yx * C + irow) * C
                                   + o0 + wc * 64 + l15;
#pragma unroll
                for (int n = 0; n < 4; ++n)
                    op[n * 16] = f2bf(acc[M][n][r] * alpha);
            }
        }
    }
#undef STAGE4
    asm volatile("s_waitcnt vmcnt(0)" ::: "memory");
}

// Two-source assembly (fallback path).
__global__ __launch_bounds__(256) void k_final(
    const unsigned short* __restrict__ Ka, int sa, int ofa,
    const unsigned short* __restrict__ Kb, int sb, int ofb,
    const float* __restrict__ Ktf, float* __restrict__ kg, int init)
{
    __shared__ float L[64 * 121];
    const int i = blockIdx.x;
    const int o0 = blockIdx.y * 64;
    const int tid = threadIdx.x, lane = tid & 63, wid = tid >> 6;

    for (int idx = tid; idx < 64 * 121; idx += 256) L[idx] = 0.f;
    __syncthreads();

    const int sa2 = sa * sa;
    for (int yxv = wid; yxv < sa2; yxv += 4) {
        float v = bf2f(Ka[((size_t)yxv * C + i) * C + o0 + lane]);
        int yy = yxv / sa + ofa, xx = yxv % sa + ofa;
        L[lane * 121 + yy * 11 + xx] += v;
    }
    __syncthreads();
    const int sb2 = sb * sb;
    for (int yxv = wid; yxv < sb2; yxv += 4) {
        float v = bf2f(Kb[((size_t)yxv * C + i) * C + o0 + lane]);
        int yy = yxv / sb + ofb, xx = yxv % sb + ofb;
        L[lane * 121 + yy * 11 + xx] += v;
    }
    __syncthreads();
    if (init) {
        for (int j = wid; j < 9; j += 4) {
            float v = Ktf[(size_t)j * C2 + (size_t)i * C + o0 + lane];
            if (j == 4 && (o0 + lane) == i) v += 1.0f;
            L[lane * 121 + (j / 3 + 4) * 11 + (j % 3 + 4)] += v;
        }
    }
    __syncthreads();
    if (init) {
        for (int idx = tid; idx < 64 * 121; idx += 256) {
            int ol = idx / 121, w = idx - ol * 121;
            kg[((size_t)(o0 + ol) * C + i) * 121 + w] = L[idx];
        }
    } else {
        for (int idx = tid; idx < 64 * 121; idx += 256) {
            int ol = idx / 121, w = idx - ol * 121;
            kg[((size_t)(o0 + ol) * C + i) * 121 + w] += L[idx];
        }
    }
}

// Fused four-source assembly (big-ws path): kg = I + K + Ki2..Ki5, one pass.
__global__ __launch_bounds__(256) void k_final4(
    const unsigned short* __restrict__ K2, const unsigned short* __restrict__ K3,
    const unsigned short* __restrict__ K4, const unsigned short* __restrict__ K5,
    const float* __restrict__ Ktf, float* __restrict__ kg)
{
    __shared__ float L[64 * 121];
    const int i = blockIdx.x;
    const int o0 = blockIdx.y * 64;
    const int tid = threadIdx.x, lane = tid & 63, wid = tid >> 6;

    for (int idx = tid; idx < 64 * 121; idx += 256) L[idx] = 0.f;
    __syncthreads();

#define ADDSRC(SRC, S, OFS) { \
        const int s2_ = (S) * (S); \
        for (int yxv = wid; yxv < s2_; yxv += 4) { \
            float v = bf2f((SRC)[((size_t)yxv * C + i) * C + o0 + lane]); \
            int yy = yxv / (S) + (OFS), xx = yxv % (S) + (OFS); \
            L[lane * 121 + yy * 11 + xx] += v; \
        } \
        __syncthreads(); \
    }
    ADDSRC(K2, 5, 3) ADDSRC(K3, 7, 2) ADDSRC(K4, 9, 1) ADDSRC(K5, 11, 0)
#undef ADDSRC

    for (int j = wid; j < 9; j += 4) {
        float v = Ktf[(size_t)j * C2 + (size_t)i * C + o0 + lane];
        if (j == 4 && (o0 + lane) == i) v += 1.0f;   // identity at (5,5)
        L[lane * 121 + (j / 3 + 4) * 11 + (j % 3 + 4)] += v;
    }
    __syncthreads();
    for (int idx = tid; idx < 64 * 121; idx += 256) {
        int ol = idx / 121, w = idx - ol * 121;
        kg[((size_t)(o0 + ol) * C + i) * 121 + w] = L[idx];
    }
}

extern "C" void kernel_launch(void* const* d_in, const int* in_sizes, int n_in,
                              void* d_out, int out_size, void* d_ws, size_t ws_size,
                              hipStream_t stream) {
    const float* K = (const float*)d_in[0];
    float* kg = (float*)d_out;
    char* ws = (char*)d_ws;

    unsigned short* Kt  = (unsigned short*)(ws);
    unsigned short* KtT = (unsigned short*)(ws + (size_t)4718592);
    float*          Ktf = (float*)         (ws + (size_t)9437184);

    const bool big = (ws_size >= (size_t)163585616);

    if (big) {
        unsigned short* Ki2 = (unsigned short*)(ws + (size_t)18874368);
        unsigned short* Ki3 = (unsigned short*)(ws + (size_t)31981568);
        unsigned short* Ki4 = (unsigned short*)(ws + (size_t)57671680);
        unsigned short* Ki5 = (unsigned short*)(ws + (size_t)100139008);
        int* sch = (int*)(ws + (size_t)163577856);
        int* ctr = sch;
        int* lst = sch + 4;

        k_transform<<<1024, 256, 0, stream>>>(K, Kt, KtT, Ktf);
        k_sched<<<1, 320, 0, stream>>>(sch);
        k_gemm<<<256, 512, 0, stream>>>(KtT, Kt, Ki2, 3, 5, 0.5f,
                                        ctr + 0, lst + 0 * 484, 100);
        k_gemm<<<256, 512, 0, stream>>>(Ki2, Kt, Ki3, 5, 7, 1.0f / 3.0f,
                                        ctr + 1, lst + 1 * 484, 196);
        k_gemm<<<256, 512, 0, stream>>>(Ki3, Kt, Ki4, 7, 9, 0.25f,
                                        ctr + 2, lst + 2 * 484, 324);
        k_gemm<<<256, 512, 0, stream>>>(Ki4, Kt, Ki5, 9, 11, 0.2f,
                                        ctr + 3, lst + 3 * 484, 484);
        k_final4<<<dim3(512, 8), 256, 0, stream>>>(Ki2, Ki3, Ki4, Ki5, Ktf, kg);
    } else {
        unsigned short* P1 = (unsigned short*)(ws + (size_t)18874368);
        unsigned short* P2 = (unsigned short*)(ws + (size_t)61341696);
        int* sch = (int*)(ws + (size_t)124780544);
        int* ctr = sch;
        int* lst = sch + 4;

        k_transform<<<1024, 256, 0, stream>>>(K, Kt, KtT, Ktf);
        k_sched<<<1, 320, 0, stream>>>(sch);
        k_gemm<<<256, 512, 0, stream>>>(KtT, Kt, P1, 3, 5, 0.5f,
                                        ctr + 0, lst + 0 * 484, 100);
        k_gemm<<<256, 512, 0, stream>>>(P1, Kt, P2, 5, 7, 1.0f / 3.0f,
                                        ctr + 1, lst + 1 * 484, 196);
        k_final<<<dim3(512, 8), 256, 0, stream>>>(P1, 5, 3, P2, 7, 2, Ktf, kg, 1);
        k_gemm<<<256, 512, 0, stream>>>(P2, Kt, P1, 7, 9, 0.25f,
                                        ctr + 2, lst + 2 * 484, 324);
        k_gemm<<<256, 512, 0, stream>>>(P1, Kt, P2, 9, 11, 0.2f,
                                        ctr + 3, lst + 3 * 484, 484);
        k_final<<<dim3(512, 8), 256, 0, stream>>>(P1, 9, 1, P2, 11, 0, Ktf, kg, 0);
    }
}

// Round 14
// 544.572 us; speedup vs baseline: 1.1217x; 1.1217x over previous
//
#include <hip/hip_runtime.h>
#include <stdint.h>

#define C 512
#define C2 262144  // 512*512

typedef __attribute__((ext_vector_type(8))) short bf16x8;
typedef __attribute__((ext_vector_type(4))) float f32x4;

__device__ __forceinline__ unsigned short f2bf(float f) {
    union { float f; uint32_t u; } v; v.f = f;
    uint32_t u = v.u;
    u += 0x7fffu + ((u >> 16) & 1u);   // round-to-nearest-even
    return (unsigned short)(u >> 16);
}
__device__ __forceinline__ float bf2f(unsigned short h) {
    union { uint32_t u; float f; } v; v.u = ((uint32_t)h) << 16;
    return v.f;
}

#define GL2LDS16(g, l) __builtin_amdgcn_global_load_lds( \
    (const __attribute__((address_space(1))) void*)(g),  \
    (__attribute__((address_space(3))) void*)(l), 16, 0, 0)

__device__ __forceinline__ bf16x8 ldsr16(const char* p) {
    bf16x8 r;
    asm volatile("ds_read_b128 %0, %1"
                 : "=v"(r)
                 : "v"((__attribute__((address_space(3))) const void*)p));
    return r;
}

__device__ __forceinline__ int nth_valid(int mask, int n) {
    int pq = 0;
    while (true) {
        if (mask & 1) { if (n == 0) return pq; --n; }
        mask >>= 1; ++pq;
    }
}

// K [o][i][3][3] fp32 ->
//   Kt  bf16 [j][o][c] = K[o][c][j]   (GEMM B operand)
//   KtT bf16 [j][i][c] = K[c][i][j]   (step-2 GEMM A operand = Ki1^T)
//   Ktf f32  [j][i][o] = K[o][i][j]   (assembly K-term, coalesced in o)
__global__ void k_transform(const float* __restrict__ K,
                            unsigned short* __restrict__ Kt,
                            unsigned short* __restrict__ KtT,
                            float* __restrict__ Ktf) {
    int t = blockIdx.x * 256 + threadIdx.x;  // t = a*512 + b
    int a = t >> 9, b = t & 511;
#pragma unroll
    for (int j = 0; j < 9; ++j) {
        float v = K[(size_t)t * 9 + j];
        unsigned short h = f2bf(v);
        Kt[(size_t)j * C2 + t] = h;
        KtT[(size_t)j * C2 + (size_t)b * C + a] = h;
        Ktf[(size_t)j * C2 + (size_t)b * C + a] = v;
    }
}

// Heavy-first work lists with chunk-splitting. Item code = yx*8 + quad*2 + isD.
// V>=6 items (on split-enabled steps) split into W chunk (first (V+1)/2 taps,
// writes Out) and D chunk (rest, writes partial buffer Pb; merged later).
// sched: int ctr[4]; combined lists at +4, offsets {0,120,400,904}, 1388 ints.
__global__ void k_sched(int* __restrict__ sched, int split_mask) {
    __shared__ int hist[4][10];
    __shared__ int base[4][10];
    const int tid = threadIdx.x;
    if (tid < 40) ((int*)hist)[tid] = 0;
    if (tid < 4) sched[tid] = 0;
    __syncthreads();
    const int offs[5] = {0, 25, 74, 155, 276};
    const int Loff[4] = {0, 120, 400, 904};
    int step = -1, yx = 0, cW = 0, cD = 0;
    if (tid < 276) {
#pragma unroll
        for (int s = 0; s < 4; ++s)
            if (tid >= offs[s] && tid < offs[s + 1]) { step = s; yx = tid - offs[s]; }
        const int s_out = 5 + 2 * step, s_in = s_out - 2;
        const int y = yx / s_out, x = yx % s_out;
        int vy = 0, vx = 0;
#pragma unroll
        for (int p = 0; p < 3; ++p) {
            if (y - p >= 0 && y - p < s_in) ++vy;
            if (x - p >= 0 && x - p < s_in) ++vx;
        }
        const int V = vy * vx;
        const bool sp = ((split_mask >> step) & 1) && (V >= 6);
        cW = sp ? (V + 1) / 2 : V;
        cD = V - cW;
        atomicAdd(&hist[step][cW], 1);
        if (cD > 0) atomicAdd(&hist[step][cD], 1);
    }
    __syncthreads();
    if (tid < 4) {
        int a = 0;
        for (int v = 9; v >= 1; --v) { base[tid][v] = a; a += hist[tid][v]; hist[tid][v] = 0; }
    }
    __syncthreads();
    if (tid < 276) {
        int* L = sched + 4 + Loff[step];
        {
            const int idx = atomicAdd(&hist[step][cW], 1);
            int* w = L + (base[step][cW] + idx) * 4;
            w[0] = yx * 8 + 0; w[1] = yx * 8 + 2; w[2] = yx * 8 + 4; w[3] = yx * 8 + 6;
        }
        if (cD > 0) {
            const int idx = atomicAdd(&hist[step][cD], 1);
            int* d = L + (base[step][cD] + idx) * 4;
            d[0] = yx * 8 + 1; d[1] = yx * 8 + 3; d[2] = yx * 8 + 5; d[3] = yx * 8 + 7;
        }
    }
}

// Merge partials: Out tile += Pb tile for every D item in list.
// grid = (n_items, 16); W items return immediately.
__global__ __launch_bounds__(256) void k_merge(
    unsigned short* __restrict__ Out, const unsigned short* __restrict__ P,
    const int* __restrict__ list)
{
    const int code = list[blockIdx.x];
    if (!(code & 1)) return;
    const int quad = (code >> 1) & 3, yx = code >> 3;
    const int i0 = (quad & 1) * 256, o0 = (quad >> 1) * 256;
    const int t = threadIdx.x;
    const int r = blockIdx.y * 16 + (t >> 4);
    const int c = (t & 15) * 16;
    const size_t base = ((size_t)yx * C + i0 + r) * C + o0 + c;
    bf16x8* po = (bf16x8*)(Out + base);
    const bf16x8* pp = (const bf16x8*)(P + base);
    bf16x8 a0 = po[0], a1 = po[1];
    bf16x8 b0 = pp[0], b1 = pp[1];
#pragma unroll
    for (int k = 0; k < 8; ++k) {
        a0[k] = (short)f2bf(bf2f((unsigned short)a0[k]) + bf2f((unsigned short)b0[k]));
        a1[k] = (short)f2bf(bf2f((unsigned short)a1[k]) + bf2f((unsigned short)b1[k]));
    }
    po[0] = a0; po[1] = a1;
}

// Persistent 256x256-tile MFMA GEMM (round-13 pipeline, unchanged schedule):
// 8 waves (2Mx4N), wave tile 128x64, K-iter=64, LDS dbuf 128KB, 1 block/CU.
// Item = (yx, quad, chunk): chunk-W covers taps [0,h), writes Out; chunk-D
// covers [h,V), writes Pb (merged by k_merge). cnt = chunk tap count.
__global__ __launch_bounds__(512, 2) void k_gemm(
    const unsigned short* __restrict__ A,   // [s_in^2][512 i][512 c] bf16
    const unsigned short* __restrict__ Bm,  // [9][512 o][512 c] bf16
    unsigned short* __restrict__ Out,       // [s_out^2][512 i][512 o] bf16
    int s_in, int s_out, float alpha,
    int* __restrict__ ctr, const int* __restrict__ list, int n_items,
    unsigned short* __restrict__ Pout, int split)
{
    __shared__ __align__(16) char lds[131072];
    __shared__ int s_item;

    const int tid = threadIdx.x;
    const int lane = tid & 63, wid = tid >> 6;
    const int wr = wid >> 2, wc = wid & 3;        // 2(M) x 4(N) waves
    const int l15 = lane & 15, lhi = lane >> 4;

    const int soff = (tid >> 3) * 1024 + ((((tid & 7) ^ ((tid >> 3) & 7))) << 4);
    const int t16 = tid * 16;

    const int coff0 = ((lhi ^ (l15 & 7)) << 4);        // par0: c 0..31
    const int coff1 = (((4 + lhi) ^ (l15 & 7)) << 4);  // par1: c 32..63
    const int aoff = wr * 16384 + l15 * 128;
    const int boff = 32768 + wc * 8192 + l15 * 128;

    const char* Abase = (const char*)A;
    const char* Bbase = (const char*)Bm;

#define STAGE4(SRC, DSTOFF) { \
        const char* s_ = (SRC) + soff; \
        GL2LDS16(s_,          lds + (DSTOFF) + t16); \
        GL2LDS16(s_ + 65536,  lds + (DSTOFF) + 8192 + t16); \
        GL2LDS16(s_ + 131072, lds + (DSTOFF) + 16384 + t16); \
        GL2LDS16(s_ + 196608, lds + (DSTOFF) + 24576 + t16); \
    }

    for (;;) {
        __syncthreads();
        if (tid == 0) s_item = atomicAdd(ctr, 1);
        __syncthreads();
        const int itm = s_item;
        if (itm >= n_items) break;
        const int code = list[itm];
        const int isD = code & 1;
        const int quad = (code >> 1) & 3;
        const int yx = code >> 3;
        const int i0 = (quad & 1) * 256, o0 = (quad >> 1) * 256;
        const int y = yx / s_out, x = yx % s_out;

        int mask = 0, V = 0;
        for (int pq = 0; pq < 9; ++pq) {
            int u = y - pq / 3, v = x - pq % 3;
            if (u >= 0 && u < s_in && v >= 0 && v < s_in) { mask |= 1 << pq; ++V; }
        }
        const int h = (split && V >= 6) ? (V + 1) / 2 : V;
        const int c0 = isD ? h : 0;
        const int cnt = isD ? (V - h) : h;
        unsigned short* ob = isD ? Pout : Out;

        auto slabA = [&](int pq) {
            int u = y - pq / 3, v = x - pq % 3;
            return Abase + ((size_t)(u * s_in + v) * C + i0) * (size_t)(C * 2);
        };
        auto slabB = [&](int pq) {
            return Bbase + ((size_t)pq * C + o0) * (size_t)(C * 2);
        };
        const int pq0 = nth_valid(mask, c0);
        const char* slA = slabA(pq0);
        const char* slB = slabB(pq0);
        const char* nsA = slA;
        const char* nsB = slB;
        if (cnt > 1) { int p1 = nth_valid(mask, c0 + 1); nsA = slabA(p1); nsB = slabB(p1); }

        f32x4 acc[8][4] = {};
        bf16x8 bBa[4], bBb[4];   // B frags par0 / par1 (one-phase-ahead)
        bf16x8 aE[4], aO[4];     // A frags (even/odd phase consumers)

        // ---- prologue: stage buf0; preload aE (mh0,par0) + bBa (par0) ----
        STAGE4(slA, 0)
        STAGE4(slB, 32768)
        asm volatile("s_waitcnt vmcnt(0)" ::: "memory");
        __builtin_amdgcn_s_barrier();
        __builtin_amdgcn_sched_barrier(0);
#pragma unroll
        for (int n = 0; n < 4; ++n)
            bBa[n] = ldsr16(lds + boff + n * 2048 + coff0);
#pragma unroll
        for (int mi = 0; mi < 4; ++mi)
            aE[mi] = ldsr16(lds + aoff + mi * 2048 + coff0);
        // no wait here: ph0's lgkm(4) drains these 8 (they are older).

        const int NI = 8 * cnt;
        for (int it = 0; it < NI; ++it) {
            const int itl = it & 7;
            const bool lastq = (itl == 7);
            const bool dummy = lastq && (((it >> 3) + 1) >= cnt);
            const char* sAe = lastq ? nsA : slA;
            const char* sBe = lastq ? nsB : slB;
            const int kb = lastq ? 0 : (itl + 1) * 128;   // next K-tile bytes
            const char* cur = lds + (it & 1) * 65536;
            const char* nxt = lds + ((it & 1) ^ 1) * 65536;

#define PHASE(PH) { \
        constexpr int mh_ = (PH) & 1; \
        constexpr int mhn_ = ((PH) + 1) & 1; \
        constexpr int parn_ = ((PH) == 3) ? 0 : (((PH) + 1) >> 1); \
        const int coffn_ = parn_ ? coff1 : coff0; \
        /* A prefetch for phase PH+1 (ph3 -> next iter ph0 from nxt buf) */ \
        { \
            const char* ab_ = ((PH) == 3) ? nxt : cur; \
            _Pragma("unroll") for (int mi = 0; mi < 4; ++mi) { \
                bf16x8 t0 = ldsr16(ab_ + aoff + mhn_ * 8192 + mi * 2048 + coffn_); \
                if constexpr (((PH) & 1) == 0) aO[mi] = t0; else aE[mi] = t0; \
            } \
        } \
        /* B prefetch: ph1 -> bBb (par1, cur), ph3 -> bBa (next par0, nxt) */ \
        if constexpr ((PH) == 1) { \
            _Pragma("unroll") for (int n = 0; n < 4; ++n) \
                bBb[n] = ldsr16(cur + boff + n * 2048 + coff1); \
        } \
        if constexpr ((PH) == 3) { \
            _Pragma("unroll") for (int n = 0; n < 4; ++n) \
                bBa[n] = ldsr16(nxt + boff + n * 2048 + coff0); \
        } \
        /* stages into nxt buf */ \
        if constexpr ((PH) == 0) { if (!dummy) STAGE4(sAe + kb, ((it & 1) ^ 1) * 65536) } \
        if constexpr ((PH) == 1) { if (!dummy) STAGE4(sBe + kb, ((it & 1) ^ 1) * 65536 + 32768) } \
        if constexpr ((PH) == 1 || (PH) == 3) { \
            asm volatile("s_waitcnt lgkmcnt(8)" ::: "memory"); \
        } else { \
            asm volatile("s_waitcnt lgkmcnt(4)" ::: "memory"); \
        } \
        __builtin_amdgcn_sched_barrier(0); \
        __builtin_amdgcn_s_setprio(1); \
        _Pragma("unroll") for (int mi = 0; mi < 4; ++mi) \
        _Pragma("unroll") for (int n = 0; n < 4; ++n) { \
            if constexpr ((PH) == 0) \
                acc[mi][n] = __builtin_amdgcn_mfma_f32_16x16x32_bf16(aE[mi], bBa[n], acc[mi][n], 0, 0, 0); \
            else if constexpr ((PH) == 1) \
                acc[4 + mi][n] = __builtin_amdgcn_mfma_f32_16x16x32_bf16(aO[mi], bBa[n], acc[4 + mi][n], 0, 0, 0); \
            else if constexpr ((PH) == 2) \
                acc[mi][n] = __builtin_amdgcn_mfma_f32_16x16x32_bf16(aE[mi], bBb[n], acc[mi][n], 0, 0, 0); \
            else \
                acc[4 + mi][n] = __builtin_amdgcn_mfma_f32_16x16x32_bf16(aO[mi], bBb[n], acc[4 + mi][n], 0, 0, 0); \
        } \
        __builtin_amdgcn_s_setprio(0); \
        if constexpr ((PH) == 2) { \
            asm volatile("s_waitcnt vmcnt(0)" ::: "memory"); \
            __builtin_amdgcn_s_barrier(); \
            __builtin_amdgcn_sched_barrier(0); \
        } \
        if constexpr ((PH) == 3) { \
            __builtin_amdgcn_s_barrier(); \
            __builtin_amdgcn_sched_barrier(0); \
        } \
    }

            PHASE(0) PHASE(1) PHASE(2) PHASE(3)
#undef PHASE

            if (lastq) {
                slA = nsA; slB = nsB;
                int vn = (it >> 3) + 2;
                if (vn < cnt) {
                    int pqn = nth_valid(mask, c0 + vn);
                    nsA = slabA(pqn); nsB = slabB(pqn);
                }
            }
        }
        // final ph3 left 8 ds_reads in flight targeting aE/bBa: drain before
        // the epilogue can reuse those registers.
        asm volatile("s_waitcnt lgkmcnt(0)" ::: "memory");
        __builtin_amdgcn_sched_barrier(0);

        // D layout per 16x16 frag: col(o)=lane&15, row(i)=(lane>>4)*4+reg
#pragma unroll
        for (int M = 0; M < 8; ++M) {
#pragma unroll
            for (int r = 0; r < 4; ++r) {
                const int irow = i0 + wr * 128 + M * 16 + lhi * 4 + r;
                unsigned short* op = ob + ((size_t)yx * C + irow) * C
                                   + o0 + wc * 64 + l15;
#pragma unroll
                for (int n = 0; n < 4; ++n)
                    op[n * 16] = f2bf(acc[M][n][r] * alpha);
            }
        }
    }
#undef STAGE4
    asm volatile("s_waitcnt vmcnt(0)" ::: "memory");
}

// Two-source assembly (fallback path).
__global__ __launch_bounds__(256) void k_final(
    const unsigned short* __restrict__ Ka, int sa, int ofa,
    const unsigned short* __restrict__ Kb, int sb, int ofb,
    const float* __restrict__ Ktf, float* __restrict__ kg, int init)
{
    __shared__ float L[64 * 121];
    const int i = blockIdx.x;
    const int o0 = blockIdx.y * 64;
    const int tid = threadIdx.x, lane = tid & 63, wid = tid >> 6;

    for (int idx = tid; idx < 64 * 121; idx += 256) L[idx] = 0.f;
    __syncthreads();

    const int sa2 = sa * sa;
    for (int yxv = wid; yxv < sa2; yxv += 4) {
        float v = bf2f(Ka[((size_t)yxv * C + i) * C + o0 + lane]);
        int yy = yxv / sa + ofa, xx = yxv % sa + ofa;
        L[lane * 121 + yy * 11 + xx] += v;
    }
    __syncthreads();
    const int sb2 = sb * sb;
    for (int yxv = wid; yxv < sb2; yxv += 4) {
        float v = bf2f(Kb[((size_t)yxv * C + i) * C + o0 + lane]);
        int yy = yxv / sb + ofb, xx = yxv % sb + ofb;
        L[lane * 121 + yy * 11 + xx] += v;
    }
    __syncthreads();
    if (init) {
        for (int j = wid; j < 9; j += 4) {
            float v = Ktf[(size_t)j * C2 + (size_t)i * C + o0 + lane];
            if (j == 4 && (o0 + lane) == i) v += 1.0f;
            L[lane * 121 + (j / 3 + 4) * 11 + (j % 3 + 4)] += v;
        }
    }
    __syncthreads();
    if (init) {
        for (int idx = tid; idx < 64 * 121; idx += 256) {
            int ol = idx / 121, w = idx - ol * 121;
            kg[((size_t)(o0 + ol) * C + i) * 121 + w] = L[idx];
        }
    } else {
        for (int idx = tid; idx < 64 * 121; idx += 256) {
            int ol = idx / 121, w = idx - ol * 121;
            kg[((size_t)(o0 + ol) * C + i) * 121 + w] += L[idx];
        }
    }
}

// Fused four-source assembly (big-ws path): kg = I + K + Ki2..Ki5, one pass.
__global__ __launch_bounds__(256) void k_final4(
    const unsigned short* __restrict__ K2, const unsigned short* __restrict__ K3,
    const unsigned short* __restrict__ K4, const unsigned short* __restrict__ K5,
    const float* __restrict__ Ktf, float* __restrict__ kg)
{
    __shared__ float L[64 * 121];
    const int i = blockIdx.x;
    const int o0 = blockIdx.y * 64;
    const int tid = threadIdx.x, lane = tid & 63, wid = tid >> 6;

    for (int idx = tid; idx < 64 * 121; idx += 256) L[idx] = 0.f;
    __syncthreads();

#define ADDSRC(SRC, S, OFS) { \
        const int s2_ = (S) * (S); \
        for (int yxv = wid; yxv < s2_; yxv += 4) { \
            float v = bf2f((SRC)[((size_t)yxv * C + i) * C + o0 + lane]); \
            int yy = yxv / (S) + (OFS), xx = yxv % (S) + (OFS); \
            L[lane * 121 + yy * 11 + xx] += v; \
        } \
        __syncthreads(); \
    }
    ADDSRC(K2, 5, 3) ADDSRC(K3, 7, 2) ADDSRC(K4, 9, 1) ADDSRC(K5, 11, 0)
#undef ADDSRC

    for (int j = wid; j < 9; j += 4) {
        float v = Ktf[(size_t)j * C2 + (size_t)i * C + o0 + lane];
        if (j == 4 && (o0 + lane) == i) v += 1.0f;   // identity at (5,5)
        L[lane * 121 + (j / 3 + 4) * 11 + (j % 3 + 4)] += v;
    }
    __syncthreads();
    for (int idx = tid; idx < 64 * 121; idx += 256) {
        int ol = idx / 121, w = idx - ol * 121;
        kg[((size_t)(o0 + ol) * C + i) * 121 + w] = L[idx];
    }
}

extern "C" void kernel_launch(void* const* d_in, const int* in_sizes, int n_in,
                              void* d_out, int out_size, void* d_ws, size_t ws_size,
                              hipStream_t stream) {
    const float* K = (const float*)d_in[0];
    float* kg = (float*)d_out;
    char* ws = (char*)d_ws;

    unsigned short* Kt  = (unsigned short*)(ws);
    unsigned short* KtT = (unsigned short*)(ws + (size_t)4718592);
    float*          Ktf = (float*)         (ws + (size_t)9437184);

    const bool big = (ws_size >= (size_t)163585616);

    if (big) {
        unsigned short* Ki2 = (unsigned short*)(ws + (size_t)18874368);
        unsigned short* Ki3 = (unsigned short*)(ws + (size_t)31981568);
        unsigned short* Ki4 = (unsigned short*)(ws + (size_t)57671680);
        unsigned short* Ki5 = (unsigned short*)(ws + (size_t)100139008);
        int* sch = (int*)(ws + (size_t)163577856);   // 5568 B of 7760 avail
        int* lst = sch + 4;
        unsigned short* Pb = Ki5;  // partials share Ki5 region (free until t5)

        k_transform<<<1024, 256, 0, stream>>>(K, Kt, KtT, Ktf);
        k_sched<<<1, 320, 0, stream>>>(sch, 0x7);   // split t2,t3,t4
        k_gemm<<<256, 512, 0, stream>>>(KtT, Kt, Ki2, 3, 5, 0.5f,
                                        sch + 0, lst + 0, 120, Pb, 1);
        k_merge<<<dim3(120, 16), 256, 0, stream>>>(Ki2, Pb, lst + 0);
        k_gemm<<<256, 512, 0, stream>>>(Ki2, Kt, Ki3, 5, 7, 1.0f / 3.0f,
                                        sch + 1, lst + 120, 280, Pb, 1);
        k_merge<<<dim3(280, 16), 256, 0, stream>>>(Ki3, Pb, lst + 120);
        k_gemm<<<256, 512, 0, stream>>>(Ki3, Kt, Ki4, 7, 9, 0.25f,
                                        sch + 2, lst + 400, 504, Pb, 1);
        k_merge<<<dim3(504, 16), 256, 0, stream>>>(Ki4, Pb, lst + 400);
        k_gemm<<<256, 512, 0, stream>>>(Ki4, Kt, Ki5, 9, 11, 0.2f,
                                        sch + 3, lst + 904, 484, Pb, 0);
        k_final4<<<dim3(512, 8), 256, 0, stream>>>(Ki2, Ki3, Ki4, Ki5, Ktf, kg);
    } else {
        unsigned short* P1 = (unsigned short*)(ws + (size_t)18874368);
        unsigned short* P2 = (unsigned short*)(ws + (size_t)61341696);
        int* sch = (int*)(ws + (size_t)124780544);
        int* lst = sch + 4;
        unsigned short* Pb2 = P2;                 // free until t3 writes it
        unsigned short* Pb3 = P1 + 6553600;       // P1 tail after Ki2 (13.1MB)

        k_transform<<<1024, 256, 0, stream>>>(K, Kt, KtT, Ktf);
        k_sched<<<1, 320, 0, stream>>>(sch, 0x3);   // split t2,t3 only
        k_gemm<<<256, 512, 0, stream>>>(KtT, Kt, P1, 3, 5, 0.5f,
                                        sch + 0, lst + 0, 120, Pb2, 1);
        k_merge<<<dim3(120, 16), 256, 0, stream>>>(P1, Pb2, lst + 0);
        k_gemm<<<256, 512, 0, stream>>>(P1, Kt, P2, 5, 7, 1.0f / 3.0f,
                                        sch + 1, lst + 120, 280, Pb3, 1);
        k_merge<<<dim3(280, 16), 256, 0, stream>>>(P2, Pb3, lst + 120);
        k_final<<<dim3(512, 8), 256, 0, stream>>>(P1, 5, 3, P2, 7, 2, Ktf, kg, 1);
        k_gemm<<<256, 512, 0, stream>>>(P2, Kt, P1, 7, 9, 0.25f,
                                        sch + 2, lst + 400, 324, Pb2, 0);
        k_gemm<<<256, 512, 0, stream>>>(P1, Kt, P2, 9, 11, 0.2f,
                                        sch + 3, lst + 904, 484, Pb2, 0);
        k_final<<<dim3(512, 8), 256, 0, stream>>>(P1, 9, 1, P2, 11, 0, Ktf, kg, 0);
    }
}

// Round 16
// 514.859 us; speedup vs baseline: 1.1864x; 1.0577x over previous
//
#include <hip/hip_runtime.h>
#include <stdint.h>

#define C 512
#define C2 262144  // 512*512

typedef __attribute__((ext_vector_type(8))) short bf16x8;
typedef __attribute__((ext_vector_type(4))) float f32x4;

__device__ __forceinline__ unsigned short f2bf(float f) {
    union { float f; uint32_t u; } v; v.f = f;
    uint32_t u = v.u;
    u += 0x7fffu + ((u >> 16) & 1u);   // round-to-nearest-even
    return (unsigned short)(u >> 16);
}
__device__ __forceinline__ float bf2f(unsigned short h) {
    union { uint32_t u; float f; } v; v.u = ((uint32_t)h) << 16;
    return v.f;
}

#define GL2LDS16(g, l) __builtin_amdgcn_global_load_lds( \
    (const __attribute__((address_space(1))) void*)(g),  \
    (__attribute__((address_space(3))) void*)(l), 16, 0, 0)

__device__ __forceinline__ bf16x8 ldsr16(const char* p) {
    bf16x8 r;
    asm volatile("ds_read_b128 %0, %1"
                 : "=v"(r)
                 : "v"((__attribute__((address_space(3))) const void*)p));
    return r;
}

__device__ __forceinline__ int nth_valid(int mask, int n) {
    int pq = 0;
    while (true) {
        if (mask & 1) { if (n == 0) return pq; --n; }
        mask >>= 1; ++pq;
    }
}

// K [o][i][3][3] fp32 ->
//   Kt  bf16 [j][o][c] = K[o][c][j]   (GEMM B operand)
//   KtT bf16 [j][i][c] = K[c][i][j]   (step-2 GEMM A operand = Ki1^T)
//   Ktf f32  [j][i][o] = K[o][i][j]   (assembly K-term, coalesced in o)
__global__ void k_transform(const float* __restrict__ K,
                            unsigned short* __restrict__ Kt,
                            unsigned short* __restrict__ KtT,
                            float* __restrict__ Ktf) {
    int t = blockIdx.x * 256 + threadIdx.x;  // t = a*512 + b
    int a = t >> 9, b = t & 511;
#pragma unroll
    for (int j = 0; j < 9; ++j) {
        float v = K[(size_t)t * 9 + j];
        unsigned short h = f2bf(v);
        Kt[(size_t)j * C2 + t] = h;
        KtT[(size_t)j * C2 + (size_t)b * C + a] = h;
        Ktf[(size_t)j * C2 + (size_t)b * C + a] = v;
    }
}

// Heavy-first chunked work lists. Entry code = yx*16 + quad*4 + j (j=chunk).
// V>=6 items on step s split into nch(s) chunks (sizes V/n + (j<V%n)).
// j==0 writes Out, j==1 -> Pb1, j==2 -> Pb2 (merged by k_merge).
// splits: 4-bit nch per step. sched: int ctr[4]; lists at +4,
// offsets {0,140,504,1008}, 1492 ints total (5984 B).
__global__ void k_sched(int* __restrict__ sched, int splits) {
    __shared__ int hist[4][10];
    __shared__ int base[4][10];
    const int tid = threadIdx.x;
    if (tid < 40) ((int*)hist)[tid] = 0;
    if (tid < 4) sched[tid] = 0;
    __syncthreads();
    const int offs[5] = {0, 25, 74, 155, 276};
    const int Loff[4] = {0, 140, 504, 1008};
    int step = -1, yx = 0, V = 0, nch = 1, bsz = 0, rem = 0;
    if (tid < 276) {
#pragma unroll
        for (int s = 0; s < 4; ++s)
            if (tid >= offs[s] && tid < offs[s + 1]) { step = s; yx = tid - offs[s]; }
        const int s_out = 5 + 2 * step, s_in = s_out - 2;
        const int y = yx / s_out, x = yx % s_out;
        int vy = 0, vx = 0;
#pragma unroll
        for (int p = 0; p < 3; ++p) {
            if (y - p >= 0 && y - p < s_in) ++vy;
            if (x - p >= 0 && x - p < s_in) ++vx;
        }
        V = vy * vx;
        const int sp = (splits >> (4 * step)) & 15;
        nch = (V >= 6 && sp > 1) ? sp : 1;
        bsz = V / nch; rem = V % nch;
        for (int j = 0; j < nch; ++j)
            atomicAdd(&hist[step][bsz + (j < rem ? 1 : 0)], 1);
    }
    __syncthreads();
    if (tid < 4) {
        int a = 0;
        for (int v = 9; v >= 1; --v) { base[tid][v] = a; a += hist[tid][v]; hist[tid][v] = 0; }
    }
    __syncthreads();
    if (tid < 276) {
        int* L = sched + 4 + Loff[step];
        for (int j = 0; j < nch; ++j) {
            const int sz = bsz + (j < rem ? 1 : 0);
            const int idx = atomicAdd(&hist[step][sz], 1);
            int* w = L + (base[step][sz] + idx) * 4;
            w[0] = yx * 16 + 0 + j; w[1] = yx * 16 + 4 + j;
            w[2] = yx * 16 + 8 + j; w[3] = yx * 16 + 12 + j;
        }
    }
}

// Merge partials into Out. One block-column per j==1 entry (single writer
// per tile); adds Pb1 and, if has3, Pb2. grid = (n_entries, 16).
__global__ __launch_bounds__(256) void k_merge(
    unsigned short* __restrict__ Out, const unsigned short* __restrict__ P1,
    const unsigned short* __restrict__ P2, const int* __restrict__ list,
    int has3)
{
    const int code = list[blockIdx.x];
    if ((code & 3) != 1) return;
    const int quad = (code >> 2) & 3, yx = code >> 4;
    const int i0 = (quad & 1) * 256, o0 = (quad >> 1) * 256;
    const int t = threadIdx.x;
    const int r = blockIdx.y * 16 + (t >> 4);
    const int c = (t & 15) * 16;
    const size_t base = ((size_t)yx * C + i0 + r) * C + o0 + c;
    bf16x8* po = (bf16x8*)(Out + base);
    const bf16x8* p1 = (const bf16x8*)(P1 + base);
    const bf16x8* p2 = (const bf16x8*)(P2 + base);
#pragma unroll
    for (int h = 0; h < 2; ++h) {
        bf16x8 a = po[h], b = p1[h];
#pragma unroll
        for (int k = 0; k < 8; ++k) {
            float s = bf2f((unsigned short)a[k]) + bf2f((unsigned short)b[k]);
            a[k] = (short)f2bf(s);
        }
        if (has3) {
            bf16x8 cvec = p2[h];
#pragma unroll
            for (int k = 0; k < 8; ++k)
                a[k] = (short)f2bf(bf2f((unsigned short)a[k]) + bf2f((unsigned short)cvec[k]));
        }
        po[h] = a;
    }
}

// Persistent 256x256-tile MFMA GEMM (round-13/14 pipeline, unchanged):
// 8 waves (2Mx4N), wave tile 128x64, K-iter=64, LDS dbuf 128KB, 1 block/CU.
// Chunk j covers taps [c0, c0+cnt); j==0 -> Out, j==1 -> Pb1, j==2 -> Pb2.
__global__ __launch_bounds__(512, 2) void k_gemm(
    const unsigned short* __restrict__ A,   // [s_in^2][512 i][512 c] bf16
    const unsigned short* __restrict__ Bm,  // [9][512 o][512 c] bf16
    unsigned short* __restrict__ Out,       // [s_out^2][512 i][512 o] bf16
    int s_in, int s_out, float alpha,
    int* __restrict__ ctr, const int* __restrict__ list, int n_items,
    unsigned short* __restrict__ Pb1, unsigned short* __restrict__ Pb2,
    int split)
{
    __shared__ __align__(16) char lds[131072];
    __shared__ int s_item;

    const int tid = threadIdx.x;
    const int lane = tid & 63, wid = tid >> 6;
    const int wr = wid >> 2, wc = wid & 3;        // 2(M) x 4(N) waves
    const int l15 = lane & 15, lhi = lane >> 4;

    const int soff = (tid >> 3) * 1024 + ((((tid & 7) ^ ((tid >> 3) & 7))) << 4);
    const int t16 = tid * 16;

    const int coff0 = ((lhi ^ (l15 & 7)) << 4);        // par0: c 0..31
    const int coff1 = (((4 + lhi) ^ (l15 & 7)) << 4);  // par1: c 32..63
    const int aoff = wr * 16384 + l15 * 128;
    const int boff = 32768 + wc * 8192 + l15 * 128;

    const char* Abase = (const char*)A;
    const char* Bbase = (const char*)Bm;

#define STAGE4(SRC, DSTOFF) { \
        const char* s_ = (SRC) + soff; \
        GL2LDS16(s_,          lds + (DSTOFF) + t16); \
        GL2LDS16(s_ + 65536,  lds + (DSTOFF) + 8192 + t16); \
        GL2LDS16(s_ + 131072, lds + (DSTOFF) + 16384 + t16); \
        GL2LDS16(s_ + 196608, lds + (DSTOFF) + 24576 + t16); \
    }

    for (;;) {
        __syncthreads();
        if (tid == 0) s_item = atomicAdd(ctr, 1);
        __syncthreads();
        const int itm = s_item;
        if (itm >= n_items) break;
        const int code = list[itm];
        const int j = code & 3;
        const int quad = (code >> 2) & 3;
        const int yx = code >> 4;
        const int i0 = (quad & 1) * 256, o0 = (quad >> 1) * 256;
        const int y = yx / s_out, x = yx % s_out;

        int mask = 0, V = 0;
        for (int pq = 0; pq < 9; ++pq) {
            int u = y - pq / 3, v = x - pq % 3;
            if (u >= 0 && u < s_in && v >= 0 && v < s_in) { mask |= 1 << pq; ++V; }
        }
        const int nch = (split > 1 && V >= 6) ? split : 1;
        const int bsz = V / nch, rem = V % nch;
        const int cnt = bsz + (j < rem ? 1 : 0);
        const int c0 = j * bsz + (j < rem ? j : rem);
        unsigned short* ob = (j == 0) ? Out : ((j == 1) ? Pb1 : Pb2);

        auto slabA = [&](int pq) {
            int u = y - pq / 3, v = x - pq % 3;
            return Abase + ((size_t)(u * s_in + v) * C + i0) * (size_t)(C * 2);
        };
        auto slabB = [&](int pq) {
            return Bbase + ((size_t)pq * C + o0) * (size_t)(C * 2);
        };
        const int pq0 = nth_valid(mask, c0);
        const char* slA = slabA(pq0);
        const char* slB = slabB(pq0);
        const char* nsA = slA;
        const char* nsB = slB;
        if (cnt > 1) { int p1 = nth_valid(mask, c0 + 1); nsA = slabA(p1); nsB = slabB(p1); }

        f32x4 acc[8][4] = {};
        bf16x8 bBa[4], bBb[4];   // B frags par0 / par1 (one-phase-ahead)
        bf16x8 aE[4], aO[4];     // A frags (even/odd phase consumers)

        // ---- prologue: stage buf0; preload aE (mh0,par0) + bBa (par0) ----
        STAGE4(slA, 0)
        STAGE4(slB, 32768)
        asm volatile("s_waitcnt vmcnt(0)" ::: "memory");
        __builtin_amdgcn_s_barrier();
        __builtin_amdgcn_sched_barrier(0);
#pragma unroll
        for (int n = 0; n < 4; ++n)
            bBa[n] = ldsr16(lds + boff + n * 2048 + coff0);
#pragma unroll
        for (int mi = 0; mi < 4; ++mi)
            aE[mi] = ldsr16(lds + aoff + mi * 2048 + coff0);
        // no wait here: ph0's lgkm(4) drains these 8 (they are older).

        const int NI = 8 * cnt;
        for (int it = 0; it < NI; ++it) {
            const int itl = it & 7;
            const bool lastq = (itl == 7);
            const bool dummy = lastq && (((it >> 3) + 1) >= cnt);
            const char* sAe = lastq ? nsA : slA;
            const char* sBe = lastq ? nsB : slB;
            const int kb = lastq ? 0 : (itl + 1) * 128;   // next K-tile bytes
            const char* cur = lds + (it & 1) * 65536;
            const char* nxt = lds + ((it & 1) ^ 1) * 65536;

#define PHASE(PH) { \
        constexpr int mh_ = (PH) & 1; \
        constexpr int mhn_ = ((PH) + 1) & 1; \
        constexpr int parn_ = ((PH) == 3) ? 0 : (((PH) + 1) >> 1); \
        const int coffn_ = parn_ ? coff1 : coff0; \
        /* A prefetch for phase PH+1 (ph3 -> next iter ph0 from nxt buf) */ \
        { \
            const char* ab_ = ((PH) == 3) ? nxt : cur; \
            _Pragma("unroll") for (int mi = 0; mi < 4; ++mi) { \
                bf16x8 t0 = ldsr16(ab_ + aoff + mhn_ * 8192 + mi * 2048 + coffn_); \
                if constexpr (((PH) & 1) == 0) aO[mi] = t0; else aE[mi] = t0; \
            } \
        } \
        /* B prefetch: ph1 -> bBb (par1, cur), ph3 -> bBa (next par0, nxt) */ \
        if constexpr ((PH) == 1) { \
            _Pragma("unroll") for (int n = 0; n < 4; ++n) \
                bBb[n] = ldsr16(cur + boff + n * 2048 + coff1); \
        } \
        if constexpr ((PH) == 3) { \
            _Pragma("unroll") for (int n = 0; n < 4; ++n) \
                bBa[n] = ldsr16(nxt + boff + n * 2048 + coff0); \
        } \
        /* stages into nxt buf */ \
        if constexpr ((PH) == 0) { if (!dummy) STAGE4(sAe + kb, ((it & 1) ^ 1) * 65536) } \
        if constexpr ((PH) == 1) { if (!dummy) STAGE4(sBe + kb, ((it & 1) ^ 1) * 65536 + 32768) } \
        if constexpr ((PH) == 1 || (PH) == 3) { \
            asm volatile("s_waitcnt lgkmcnt(8)" ::: "memory"); \
        } else { \
            asm volatile("s_waitcnt lgkmcnt(4)" ::: "memory"); \
        } \
        __builtin_amdgcn_sched_barrier(0); \
        __builtin_amdgcn_s_setprio(1); \
        _Pragma("unroll") for (int mi = 0; mi < 4; ++mi) \
        _Pragma("unroll") for (int n = 0; n < 4; ++n) { \
            if constexpr ((PH) == 0) \
                acc[mi][n] = __builtin_amdgcn_mfma_f32_16x16x32_bf16(aE[mi], bBa[n], acc[mi][n], 0, 0, 0); \
            else if constexpr ((PH) == 1) \
                acc[4 + mi][n] = __builtin_amdgcn_mfma_f32_16x16x32_bf16(aO[mi], bBa[n], acc[4 + mi][n], 0, 0, 0); \
            else if constexpr ((PH) == 2) \
                acc[mi][n] = __builtin_amdgcn_mfma_f32_16x16x32_bf16(aE[mi], bBb[n], acc[mi][n], 0, 0, 0); \
            else \
                acc[4 + mi][n] = __builtin_amdgcn_mfma_f32_16x16x32_bf16(aO[mi], bBb[n], acc[4 + mi][n], 0, 0, 0); \
        } \
        __builtin_amdgcn_s_setprio(0); \
        if constexpr ((PH) == 2) { \
            asm volatile("s_waitcnt vmcnt(0)" ::: "memory"); \
            __builtin_amdgcn_s_barrier(); \
            __builtin_amdgcn_sched_barrier(0); \
        } \
        if constexpr ((PH) == 3) { \
            __builtin_amdgcn_s_barrier(); \
            __builtin_amdgcn_sched_barrier(0); \
        } \
    }

            PHASE(0) PHASE(1) PHASE(2) PHASE(3)
#undef PHASE

            if (lastq) {
                slA = nsA; slB = nsB;
                int vn = (it >> 3) + 2;
                if (vn < cnt) {
                    int pqn = nth_valid(mask, c0 + vn);
                    nsA = slabA(pqn); nsB = slabB(pqn);
                }
            }
        }
        // final ph3 left 8 ds_reads in flight targeting aE/bBa: drain before
        // the epilogue can reuse those registers.
        asm volatile("s_waitcnt lgkmcnt(0)" ::: "memory");
        __builtin_amdgcn_sched_barrier(0);

        // D layout per 16x16 frag: col(o)=lane&15, row(i)=(lane>>4)*4+reg
#pragma unroll
        for (int M = 0; M < 8; ++M) {
#pragma unroll
            for (int r = 0; r < 4; ++r) {
                const int irow = i0 + wr * 128 + M * 16 + lhi * 4 + r;
                unsigned short* op = ob + ((size_t)yx * C + irow) * C
                                   + o0 + wc * 64 + l15;
#pragma unroll
                for (int n = 0; n < 4; ++n)
                    op[n * 16] = f2bf(acc[M][n][r] * alpha);
            }
        }
    }
#undef STAGE4
    asm volatile("s_waitcnt vmcnt(0)" ::: "memory");
}

// Two-source assembly (fallback path, unchanged).
__global__ __launch_bounds__(256) void k_final(
    const unsigned short* __restrict__ Ka, int sa, int ofa,
    const unsigned short* __restrict__ Kb, int sb, int ofb,
    const float* __restrict__ Ktf, float* __restrict__ kg, int init)
{
    __shared__ float L[64 * 121];
    const int i = blockIdx.x;
    const int o0 = blockIdx.y * 64;
    const int tid = threadIdx.x, lane = tid & 63, wid = tid >> 6;

    for (int idx = tid; idx < 64 * 121; idx += 256) L[idx] = 0.f;
    __syncthreads();

    const int sa2 = sa * sa;
    for (int yxv = wid; yxv < sa2; yxv += 4) {
        float v = bf2f(Ka[((size_t)yxv * C + i) * C + o0 + lane]);
        int yy = yxv / sa + ofa, xx = yxv % sa + ofa;
        L[lane * 121 + yy * 11 + xx] += v;
    }
    __syncthreads();
    const int sb2 = sb * sb;
    for (int yxv = wid; yxv < sb2; yxv += 4) {
        float v = bf2f(Kb[((size_t)yxv * C + i) * C + o0 + lane]);
        int yy = yxv / sb + ofb, xx = yxv % sb + ofb;
        L[lane * 121 + yy * 11 + xx] += v;
    }
    __syncthreads();
    if (init) {
        for (int j = wid; j < 9; j += 4) {
            float v = Ktf[(size_t)j * C2 + (size_t)i * C + o0 + lane];
            if (j == 4 && (o0 + lane) == i) v += 1.0f;
            L[lane * 121 + (j / 3 + 4) * 11 + (j % 3 + 4)] += v;
        }
    }
    __syncthreads();
    if (init) {
        for (int idx = tid; idx < 64 * 121; idx += 256) {
            int ol = idx / 121, w = idx - ol * 121;
            kg[((size_t)(o0 + ol) * C + i) * 121 + w] = L[idx];
        }
    } else {
        for (int idx = tid; idx < 64 * 121; idx += 256) {
            int ol = idx / 121, w = idx - ol * 121;
            kg[((size_t)(o0 + ol) * C + i) * 121 + w] += L[idx];
        }
    }
}

// Fused four-source assembly, VECTORIZED loads: each lane reads bf16x8
// (8 consecutive o), 8 rows per wave-instr -> 1KB/instr coalescing.
// (l3,yxv) -> (row block, w) is injective: no LDS write races.
__global__ __launch_bounds__(256) void k_final4(
    const unsigned short* __restrict__ K2, const unsigned short* __restrict__ K3,
    const unsigned short* __restrict__ K4, const unsigned short* __restrict__ K5,
    const float* __restrict__ Ktf, float* __restrict__ kg)
{
    __shared__ float L[64 * 121];
    const int i = blockIdx.x;
    const int o0 = blockIdx.y * 64;
    const int tid = threadIdx.x, lane = tid & 63, wid = tid >> 6;

    for (int idx = tid; idx < 64 * 121; idx += 256) L[idx] = 0.f;
    __syncthreads();

#define ADDSRC(SRC, S, OFS) { \
        const int total_ = (S) * (S) * 8; \
        for (int idx = tid; idx < total_; idx += 256) { \
            const int yxv = idx >> 3, l3 = idx & 7; \
            bf16x8 v = *(const bf16x8*)&(SRC)[((size_t)yxv * C + i) * C + o0 + l3 * 8]; \
            const int w = (yxv / (S) + (OFS)) * 11 + yxv % (S) + (OFS); \
            _Pragma("unroll") for (int k = 0; k < 8; ++k) \
                L[(l3 * 8 + k) * 121 + w] += bf2f((unsigned short)v[k]); \
        } \
        __syncthreads(); \
    }
    ADDSRC(K2, 5, 3) ADDSRC(K3, 7, 2) ADDSRC(K4, 9, 1) ADDSRC(K5, 11, 0)
#undef ADDSRC

    for (int j = wid; j < 9; j += 4) {
        float v = Ktf[(size_t)j * C2 + (size_t)i * C + o0 + lane];
        if (j == 4 && (o0 + lane) == i) v += 1.0f;   // identity at (5,5)
        L[lane * 121 + (j / 3 + 4) * 11 + (j % 3 + 4)] += v;
    }
    __syncthreads();
    for (int idx = tid; idx < 64 * 121; idx += 256) {
        int ol = idx / 121, w = idx - ol * 121;
        kg[((size_t)(o0 + ol) * C + i) * 121 + w] = L[idx];
    }
}

extern "C" void kernel_launch(void* const* d_in, const int* in_sizes, int n_in,
                              void* d_out, int out_size, void* d_ws, size_t ws_size,
                              hipStream_t stream) {
    const float* K = (const float*)d_in[0];
    float* kg = (float*)d_out;
    char* ws = (char*)d_ws;

    unsigned short* Kt  = (unsigned short*)(ws);
    unsigned short* KtT = (unsigned short*)(ws + (size_t)4718592);
    float*          Ktf = (float*)         (ws + (size_t)9437184);

    const bool big = (ws_size >= (size_t)163585616);

    if (big) {
        unsigned short* Ki2 = (unsigned short*)(ws + (size_t)18874368);
        unsigned short* Ki3 = (unsigned short*)(ws + (size_t)31981568);
        unsigned short* Ki4 = (unsigned short*)(ws + (size_t)57671680);   // 42.5MB
        unsigned short* Ki5 = (unsigned short*)(ws + (size_t)100139008);  // 63.4MB
        int* sch = (int*)(ws + (size_t)163577856);   // 5984 B of 7760 avail
        int* lst = sch + 4;
        // Partial placement (IN-BOUNDS, round-15 crash fix):
        //   PbA = Ki5 region (free until t5; t4 partial 42.5MB <= 63.4MB)
        //   PbB = Ki4 region (free until t4; t2 13.1MB / t3 25.7MB <= 42.5MB)
        // Each stale partial is overwritten by the later GEMM owning the region.
        unsigned short* PbA = Ki5;
        unsigned short* PbB = Ki4;

        k_transform<<<1024, 256, 0, stream>>>(K, Kt, KtT, Ktf);
        // splits: t2=3, t3=3, t4=2, t5=1
        k_sched<<<1, 320, 0, stream>>>(sch, 0x1233);
        k_gemm<<<256, 512, 0, stream>>>(KtT, Kt, Ki2, 3, 5, 0.5f,
                                        sch + 0, lst + 0, 140, PbA, PbB, 3);
        k_merge<<<dim3(140, 16), 256, 0, stream>>>(Ki2, PbA, PbB, lst + 0, 1);
        k_gemm<<<256, 512, 0, stream>>>(Ki2, Kt, Ki3, 5, 7, 1.0f / 3.0f,
                                        sch + 1, lst + 140, 364, PbA, PbB, 3);
        k_merge<<<dim3(364, 16), 256, 0, stream>>>(Ki3, PbA, PbB, lst + 140, 1);
        k_gemm<<<256, 512, 0, stream>>>(Ki3, Kt, Ki4, 7, 9, 0.25f,
                                        sch + 2, lst + 504, 504, PbA, PbA, 2);
        k_merge<<<dim3(504, 16), 256, 0, stream>>>(Ki4, PbA, PbA, lst + 504, 0);
        k_gemm<<<256, 512, 0, stream>>>(Ki4, Kt, Ki5, 9, 11, 0.2f,
                                        sch + 3, lst + 1008, 484, PbA, PbA, 1);
        k_final4<<<dim3(512, 8), 256, 0, stream>>>(Ki2, Ki3, Ki4, Ki5, Ktf, kg);
    } else {
        unsigned short* P1 = (unsigned short*)(ws + (size_t)18874368);
        unsigned short* P2 = (unsigned short*)(ws + (size_t)61341696);
        int* sch = (int*)(ws + (size_t)124780544);
        int* lst = sch + 4;
        unsigned short* Pb2 = P2;                 // free until t3 writes it
        unsigned short* Pb3 = P1 + 6553600;       // P1 tail after Ki2 (13.1MB)

        k_transform<<<1024, 256, 0, stream>>>(K, Kt, KtT, Ktf);
        // splits: t2=2, t3=2, t4=1, t5=1
        k_sched<<<1, 320, 0, stream>>>(sch, 0x1122);
        k_gemm<<<256, 512, 0, stream>>>(KtT, Kt, P1, 3, 5, 0.5f,
                                        sch + 0, lst + 0, 140, Pb2, Pb2, 2);
        k_merge<<<dim3(140, 16), 256, 0, stream>>>(P1, Pb2, Pb2, lst + 0, 0);
        k_gemm<<<256, 512, 0, stream>>>(P1, Kt, P2, 5, 7, 1.0f / 3.0f,
                                        sch + 1, lst + 140, 364, Pb3, Pb3, 2);
        k_merge<<<dim3(364, 16), 256, 0, stream>>>(P2, Pb3, Pb3, lst + 140, 0);
        k_final<<<dim3(512, 8), 256, 0, stream>>>(P1, 5, 3, P2, 7, 2, Ktf, kg, 1);
        k_gemm<<<256, 512, 0, stream>>>(P2, Kt, P1, 7, 9, 0.25f,
                                        sch + 2, lst + 504, 324, Pb2, Pb2, 1);
        k_gemm<<<256, 512, 0, stream>>>(P1, Kt, P2, 9, 11, 0.2f,
                                        sch + 3, lst + 1008, 484, Pb2, Pb2, 1);
        k_final<<<dim3(512, 8), 256, 0, stream>>>(P1, 9, 1, P2, 11, 0, Ktf, kg, 0);
    }
}